// Round 1
// baseline (1692.038 us; speedup 1.0000x reference)
//
#include <hip/hip_runtime.h>

// MaxUnpooling2D: updates [8,256,256,64] f32, mask int32 same shape
// (flattened index into the [oH*oW*C] = [512*512*64] plane).
// out [8,512,512,64] f32, scatter-ADD (duplicates sum).
//
// Decode: y = m/(oW*C); x = (m/C)%oW; channel = own c; batch = own b.
// Since C=64 (pow2) and m < oH*oW*C: y*(oW*C)+x*C == m & ~63.
// out_idx = b*(oH*oW*C) + (m & ~63) + c.

static constexpr int N_ELEM   = 8 * 256 * 256 * 64;   // 33,554,432
static constexpr int PER_B    = 256 * 256 * 64;       // 4,194,304  (in-plane per batch)
static constexpr int OUT_PER_B = 512 * 512 * 64;      // 16,777,216 (out-plane per batch)

__global__ void unpool_scatter(const float* __restrict__ upd,
                               const int*  __restrict__ mask,
                               float*      __restrict__ out) {
    int i = blockIdx.x * blockDim.x + threadIdx.x;   // vec4 index
    int base = i << 2;                               // element index of lane's first elem
    if (base >= N_ELEM) return;

    const int4   m = reinterpret_cast<const int4*>(mask)[i];
    const float4 u = reinterpret_cast<const float4*>(upd)[i];

    int b = base / PER_B;                 // PER_B = 1<<22
    int c = base & 63;                    // 4 consecutive elems stay in one channel block
    size_t obase = (size_t)b * OUT_PER_B + c;

    atomicAdd(&out[obase + (size_t)(m.x & ~63)    ], u.x);
    atomicAdd(&out[obase + (size_t)(m.y & ~63) + 1], u.y);
    atomicAdd(&out[obase + (size_t)(m.z & ~63) + 2], u.z);
    atomicAdd(&out[obase + (size_t)(m.w & ~63) + 3], u.w);
}

extern "C" void kernel_launch(void* const* d_in, const int* in_sizes, int n_in,
                              void* d_out, int out_size, void* d_ws, size_t ws_size,
                              hipStream_t stream) {
    const float* upd  = (const float*)d_in[0];
    const int*   mask = (const int*)d_in[1];
    float*       out  = (float*)d_out;

    // Output must be zero before scatter-add (harness poisons 0xAA; duplicates sum).
    hipMemsetAsync(out, 0, (size_t)out_size * sizeof(float), stream);

    int n4 = N_ELEM / 4;                  // 8,388,608 vec4 units
    int block = 256;
    int grid = (n4 + block - 1) / block;  // 32768 blocks
    unpool_scatter<<<grid, block, 0, stream>>>(upd, mask, out);
}